// Round 8
// baseline (2662.028 us; speedup 1.0000x reference)
//
#include <hip/hip_runtime.h>
#include <cmath>

#define ACT_NONE 0
#define ACT_GELU 1
#define ACT_RELU 2

// d_out layout (floats):
//  centers[0,1600) wh[1600,3200) angles[3200,4000) cls[4000,16000)
//  conf[16000,16800) tops[16800,17600) fisher[17600,222400)
#define OFF_CENTERS 0
#define OFF_WH      1600
#define OFF_ANG     3200
#define OFF_CLS     4000
#define OFF_CONF    16000
#define OFF_TOPS    16800
#define OFF_FISH    17600

__device__ __forceinline__ float gelu_f(float v) {
    return 0.5f * v * (1.f + erff(v * 0.70710678118654752f));
}

// ---------------- fused prep: all weight transposes (BN-folded) + biases in ONE launch
__device__ __forceinline__ void wtr_seg(const float* __restrict__ w, const float* __restrict__ g,
                                        float* __restrict__ dst, int O, int I9, int j) {
    const int o = j / I9, r = j % I9;
    float s = 1.f;
    if (g) {
        double sq = sqrt(1.0 + 1e-5);
        s = g[o] / (float)sq;
    }
    dst[(size_t)r * O + o] = w[(size_t)o * I9 + r] * s;
}
__device__ __forceinline__ void btr_seg(const float* __restrict__ b, const float* __restrict__ g,
                                        const float* __restrict__ bb, float* __restrict__ dst, int o) {
    double sq = sqrt(1.0 + 1e-5);
    const float s = g[o] / (float)sq;
    dst[o] = b[o] * s + bb[o];
}

__global__ __launch_bounds__(256) void prep_all_k(
    const float* ew1, const float* g1, const float* ew2, const float* g2,
    const float* ew3, const float* g3, const float* fw,  const float* gf,
    const float* dw,  const float* sw,
    const float* eb1, const float* bb1, const float* eb2, const float* bb2,
    const float* eb3, const float* bb3, const float* fb,  const float* bbf,
    float* wt1, float* wt2, float* wt3, float* wtf, float* wtd, float* wts,
    float* ob1, float* ob2, float* ob3, float* obf)
{
    int i = blockIdx.x * 256 + threadIdx.x;
    if (i < 864)    { wtr_seg(ew1, g1, wt1, 32, 27, i);    return; }  i -= 864;
    if (i < 18432)  { wtr_seg(ew2, g2, wt2, 64, 288, i);   return; }  i -= 18432;
    if (i < 73728)  { wtr_seg(ew3, g3, wt3, 128, 576, i);  return; }  i -= 73728;
    if (i < 147456) { wtr_seg(fw,  gf, wtf, 128, 1152, i); return; }  i -= 147456;
    if (i < 73728)  { wtr_seg(dw, nullptr, wtd, 64, 1152, i); return; } i -= 73728;
    if (i < 74304)  { wtr_seg(sw, nullptr, wts, 64, 1161, i); return; } i -= 74304;
    if (i < 32)     { btr_seg(eb1, g1, bb1, ob1, i); return; }  i -= 32;
    if (i < 64)     { btr_seg(eb2, g2, bb2, ob2, i); return; }  i -= 64;
    if (i < 128)    { btr_seg(eb3, g3, bb3, ob3, i); return; }  i -= 128;
    if (i < 128)    { btr_seg(fb,  gf, bbf, obf, i); return; }
}

// ---------------- zero helpers
__device__ __forceinline__ void zcol(float* __restrict__ buf, int W, int H, int j) {
    const int p = j / (H * 2), r = j % (H * 2);
    const int y = r >> 1, side = r & 1;
    buf[(size_t)p * W * H + (size_t)y * W + (side ? W - 1 : 0)] = 0.f;
}

// upfront: zrow + P1/P2/P3 pad columns in ONE launch
__global__ __launch_bounds__(256) void zero_pads_k(
    float* zrow, float* p1, float* p2, float* p3)
{
    int i = blockIdx.x * 256 + threadIdx.x;
    if (i < 32) { zrow[i] = 0.f; return; }          i -= 32;
    if (i < 256 * 320 * 2)  { zcol(p1, 322, 320, i); return; }  i -= 256 * 320 * 2;
    if (i < 512 * 160 * 2)  { zcol(p2, 162, 160, i); return; }  i -= 512 * 160 * 2;
    if (i < 1024 * 160 * 2) { zcol(p3, 162, 160, i); return; }
}

__global__ void zero_cols_k(float* __restrict__ buf, int nplanes, int W, int H) {
    int i = blockIdx.x * 256 + threadIdx.x;
    if (i >= nplanes * H * 2) return;
    zcol(buf, W, H, i);
}

__global__ void zero_fill_k(float* __restrict__ buf, int n) {
    int i = blockIdx.x * 256 + threadIdx.x;
    if (i < n) buf[i] = 0.f;
}

// ---------------- checked direct conv (conv1 only: 3->32, stride2, raw images)
template<int CIN, int COUT, int CHUNK, int STRIDE, int HOUT, int WOUT, int ACT, bool OPADX>
__global__ __launch_bounds__(256) void conv3x3_k(
    const float* __restrict__ in, const float* __restrict__ wt,
    const float* __restrict__ bias, float* __restrict__ out)
{
    constexpr int HIN = HOUT * STRIDE, WIN = WOUT * STRIDE;
    constexpr int NCH = COUT / CHUNK;
    const int tx = threadIdx.x & 15, ty = threadIdx.x >> 4;
    const int x = blockIdx.x * 16 + tx;
    const int y = blockIdx.y * 16 + ty;
    const int b = blockIdx.z / NCH;
    const int co0 = (blockIdx.z % NCH) * CHUNK;

    float acc[CHUNK];
#pragma unroll
    for (int c = 0; c < CHUNK; ++c) acc[c] = bias[co0 + c];

    const float* inb = in + (size_t)b * CIN * HIN * WIN;
#pragma unroll 1
    for (int ci = 0; ci < CIN; ++ci) {
        const float* ip = inb + (size_t)ci * HIN * WIN;
#pragma unroll
        for (int ky = 0; ky < 3; ++ky) {
            const int iy = y * STRIDE + ky - 1;
            const bool yok = (unsigned)iy < (unsigned)HIN;
#pragma unroll
            for (int kx = 0; kx < 3; ++kx) {
                const int ix = x * STRIDE + kx - 1;
                const bool ok = yok && ((unsigned)ix < (unsigned)WIN);
                const float v = ok ? ip[(size_t)iy * WIN + ix] : 0.f;
                const float* wp = wt + ((size_t)(ci * 9 + ky * 3 + kx)) * COUT + co0;
#pragma unroll
                for (int c = 0; c < CHUNK; ++c) acc[c] = fmaf(v, wp[c], acc[c]);
            }
        }
    }
#pragma unroll
    for (int c = 0; c < CHUNK; ++c) {
        float v = acc[c];
        if (ACT == ACT_GELU) v = gelu_f(v);
        if (ACT == ACT_RELU) v = fmaxf(v, 0.f);
        if (OPADX) {
            out[((size_t)b * COUT + co0 + c) * (size_t)(HOUT * (WOUT + 2))
                + (size_t)y * (WOUT + 2) + (x + 1)] = v;
        } else {
            out[((size_t)b * COUT + co0 + c) * (size_t)(HOUT * WOUT)
                + (size_t)y * WOUT + x] = v;
        }
    }
}

// ---------------- x-padded conv v4: scalar weights, 4-px strips, 64 acc,
// zero-row pointer select, PING-PONG channel prefetch (loads ci+1 issue
// before ci's FMA block -> HBM/L2 latency hides under 576 FMAs)
#define FMA16(A, V, W0, W1, W2, W3) do { \
  A[0]=fmaf((V),(W0).x,A[0]); A[1]=fmaf((V),(W0).y,A[1]); A[2]=fmaf((V),(W0).z,A[2]); A[3]=fmaf((V),(W0).w,A[3]); \
  A[4]=fmaf((V),(W1).x,A[4]); A[5]=fmaf((V),(W1).y,A[5]); A[6]=fmaf((V),(W1).z,A[6]); A[7]=fmaf((V),(W1).w,A[7]); \
  A[8]=fmaf((V),(W2).x,A[8]); A[9]=fmaf((V),(W2).y,A[9]); A[10]=fmaf((V),(W2).z,A[10]); A[11]=fmaf((V),(W2).w,A[11]); \
  A[12]=fmaf((V),(W3).x,A[12]); A[13]=fmaf((V),(W3).y,A[13]); A[14]=fmaf((V),(W3).z,A[14]); A[15]=fmaf((V),(W3).w,A[15]); \
} while (0)

template<int CIN, int COUT, int S, int PW, int HIN, int ACT, bool EXTRA, bool OPAD>
__global__ __launch_bounds__(256) void conv4_k(
    const float* __restrict__ in, const float* __restrict__ extra,
    const float* __restrict__ wt, const float* __restrict__ bias,
    const float* __restrict__ zrow, float* __restrict__ out)
{
    constexpr int PPIN = HIN * PW;
    constexpr int CHUNK = 16, NCH = COUT / CHUNK;
    constexpr int CTOT = CIN + (EXTRA ? 1 : 0);
    constexpr int NL = 3 * S + 3;   // 6 (S=1) or 9 (S=2)
    const int tx = threadIdx.x & 7, ty = threadIdx.x >> 3;
    const int ox0 = blockIdx.x * 32 + tx * 4;          // 4 output px per thread
    const int oy  = blockIdx.y * 32 + ty;
    const int b   = blockIdx.z / NCH;
    const int co0 = (blockIdx.z % NCH) * CHUNK;

    float acc[4][16];
#pragma unroll
    for (int c = 0; c < 16; ++c) {
        const float bv = bias[co0 + c];
#pragma unroll
        for (int p = 0; p < 4; ++p) acc[p][c] = bv;
    }

    int rowoff[3], rok[3];
#pragma unroll
    for (int r = 0; r < 3; ++r) {
        const int riy = oy * S + r - 1;
        rok[r] = (riy >= 0 && riy < HIN) ? 1 : 0;
        const int rr = riy < 0 ? 0 : (riy >= HIN ? HIN - 1 : riy);
        rowoff[r] = rr * PW + ox0 * S;      // even -> float2-aligned
    }

    const float* inb = in + (size_t)b * CIN * PPIN;
    const float* wb  = wt + co0;

    auto chptr = [&](int ci) -> const float* {
        return (EXTRA && ci == CIN) ? (extra + (size_t)b * PPIN)
                                    : (inb + (size_t)ci * PPIN);
    };
    auto ldch = [&](const float* chp, float vv[3][NL]) {
#pragma unroll
        for (int r = 0; r < 3; ++r) {
            const float* pr = rok[r] ? (chp + rowoff[r]) : zrow;
#pragma unroll
            for (int j = 0; j < NL / 2; ++j) {
                const float2 t = *(const float2*)(pr + 2 * j);
                vv[r][2 * j] = t.x; vv[r][2 * j + 1] = t.y;
            }
            if (NL & 1) vv[r][NL - 1] = pr[NL - 1];
        }
    };
    auto fmach = [&](const float vv[3][NL], int ci) {
        const float* wr = wb + (size_t)(ci * 9) * COUT;
#pragma unroll
        for (int ky = 0; ky < 3; ++ky) {
#pragma unroll
            for (int kx = 0; kx < 3; ++kx) {
                const float* wp = wr + (size_t)(ky * 3 + kx) * COUT;  // uniform -> SGPR
                const float4 w0 = *(const float4*)(wp);
                const float4 w1 = *(const float4*)(wp + 4);
                const float4 w2 = *(const float4*)(wp + 8);
                const float4 w3 = *(const float4*)(wp + 12);
#pragma unroll
                for (int p = 0; p < 4; ++p) {
                    const float a = vv[ky][p * S + kx];
                    FMA16(acc[p], a, w0, w1, w2, w3);
                }
            }
        }
    };

    float v0[3][NL], v1[3][NL];
    ldch(chptr(0), v0);
#pragma unroll 1
    for (int ci = 0; ci < CTOT; ci += 2) {
        if (ci + 1 < CTOT) ldch(chptr(ci + 1), v1);     // prefetch ci+1
        fmach(v0, ci);
        if (ci + 1 < CTOT) {
            if (ci + 2 < CTOT) ldch(chptr(ci + 2), v0); // prefetch ci+2
            fmach(v1, ci + 1);
        }
    }

#pragma unroll
    for (int c = 0; c < 16; ++c) {
#pragma unroll
        for (int p = 0; p < 4; ++p) {
            float u = acc[p][c];
            if (ACT == ACT_GELU) u = gelu_f(u);
            if (ACT == ACT_RELU) u = fmaxf(u, 0.f);
            if (OPAD) {
                out[((size_t)b * COUT + co0 + c) * (160 * 162)
                    + (size_t)oy * 162 + (ox0 + p + 1)] = u;
            } else {
                out[((size_t)b * COUT + co0 + c) * (160 * 160)
                    + (size_t)oy * 160 + (ox0 + p)] = u;
            }
        }
    }
}

// ---------------- dist 1x1 conv (64->15) + analytic Fisher map, fused
__global__ __launch_bounds__(256) void dist2_fisher_k(
    const float* __restrict__ hid, const float* __restrict__ w /*15x64*/,
    const float* __restrict__ b2 /*15*/, const float* __restrict__ temp,
    float* __restrict__ fisher_out, float* __restrict__ fisher_pad)
{
    const int p = blockIdx.x * 256 + threadIdx.x;
    if (p >= 8 * 25600) return;
    const int bi = p / 25600, pix = p % 25600;
    const float* h = hid + (size_t)bi * 64 * 25600 + pix;
    float hv[64];
#pragma unroll
    for (int i = 0; i < 64; ++i) hv[i] = h[(size_t)i * 25600];
    const float t = fminf(fmaxf(temp[0], 0.1f), 10.f);
    const float inv_t = 1.f / t;
    float fsum = 0.f;
#pragma unroll 1
    for (int c = 0; c < 15; ++c) {
        float l = b2[c];
        const float* wr = w + c * 64;
#pragma unroll
        for (int i = 0; i < 64; ++i) l = fmaf(hv[i], wr[i], l);
        const float pr = 1.f / (1.f + expf(-l * inv_t));
        fsum += fmaxf(pr * (1.f - pr), 1e-6f);
    }
    fisher_out[p] = fsum;
    const int yy = pix / 160, xx = pix % 160;
    fisher_pad[(size_t)bi * (160 * 162) + (size_t)yy * 162 + (xx + 1)] = fsum;
}

// ---------------- score 1x1 conv (64->1) + sigmoid
__global__ __launch_bounds__(256) void score2_k(
    const float* __restrict__ hid, const float* __restrict__ w /*64*/,
    const float* __restrict__ b, float* __restrict__ sc)
{
    const int p = blockIdx.x * 256 + threadIdx.x;
    if (p >= 8 * 25600) return;
    const int bi = p / 25600, pix = p % 25600;
    const float* h = hid + (size_t)bi * 64 * 25600 + pix;
    float a = b[0];
#pragma unroll
    for (int i = 0; i < 64; ++i) a = fmaf(h[(size_t)i * 25600], w[i], a);
    sc[p] = 1.f / (1.f + expf(-a));
}

// ---------------- per-batch top-100 via 4-pass MSB radix select
#define TK_CAP 512
__global__ __launch_bounds__(256) void topk_radix_k(
    const float* __restrict__ scores, float* __restrict__ topv, int* __restrict__ topi)
{
    __shared__ unsigned hist[256];
    __shared__ unsigned gv[128]; __shared__ int gi[128];
    __shared__ unsigned ecnt[2];
    __shared__ int ei_[TK_CAP];
    __shared__ unsigned fv[100]; __shared__ int fi[100];
    __shared__ unsigned sel_prefix; __shared__ int sel_remaining;
    const int b = blockIdx.x, t = threadIdx.x;
    const float* s = scores + (size_t)b * 25600;

    unsigned prefix = 0; int remaining = 100;
    for (int pass = 0; pass < 4; ++pass) {
        const int shift = 24 - 8 * pass;
        hist[t] = 0;
        __syncthreads();
        const unsigned pmask = (pass == 0) ? 0u : (0xFFFFFFFFu << (shift + 8));
        for (int i = t; i < 25600; i += 256) {
            const unsigned k = __float_as_uint(s[i]);
            if ((k & pmask) == prefix)
                atomicAdd(&hist[(k >> shift) & 255], 1u);
        }
        __syncthreads();
        if (t == 0) {
            unsigned cum = 0; int bkt = 0;
            for (int d = 255; d >= 0; --d) {
                const unsigned c = hist[d];
                if (cum + c >= (unsigned)remaining) { bkt = d; break; }
                cum += c;
            }
            sel_prefix = prefix | ((unsigned)bkt << shift);
            sel_remaining = remaining - (int)cum;
        }
        __syncthreads();
        prefix = sel_prefix; remaining = sel_remaining;
        __syncthreads();
    }
    if (t == 0) { ecnt[0] = 0; ecnt[1] = 0; }
    __syncthreads();
    for (int i = t; i < 25600; i += 256) {
        const unsigned k = __float_as_uint(s[i]);
        if (k > prefix) {
            const unsigned p = atomicAdd(&ecnt[0], 1u);
            gv[p] = k; gi[p] = i;
        } else if (k == prefix) {
            const unsigned p = atomicAdd(&ecnt[1], 1u);
            if (p < TK_CAP) ei_[p] = i;
        }
    }
    __syncthreads();
    const int cG = (int)ecnt[0];
    const int cE = (int)ecnt[1] < TK_CAP ? (int)ecnt[1] : TK_CAP;
    if (t < cG) { fv[t] = gv[t]; fi[t] = gi[t]; }
    if (t < cE) {
        const int idx = ei_[t]; int r = 0;
        for (int l = 0; l < cE; ++l) r += (ei_[l] < idx) ? 1 : 0;
        if (r < remaining) { fv[cG + r] = prefix; fi[cG + r] = idx; }
    }
    __syncthreads();
    if (t < 100) {
        const unsigned myv = fv[t]; const int myi = fi[t]; int r = 0;
        for (int l = 0; l < 100; ++l) {
            const unsigned v = fv[l]; const int li = fi[l];
            r += (v > myv || (v == myv && li < myi)) ? 1 : 0;
        }
        topv[b * 100 + r] = __uint_as_float(myv);
        topi[b * 100 + r] = myi;
    }
}

// ---------------- per-proposal heads: one block per (b,k), 128 threads
// features is x-padded (B,128,160,162)
__global__ __launch_bounds__(128) void heads_k(
    const float* __restrict__ features, const float* __restrict__ topv,
    const int* __restrict__ topi,
    const float* __restrict__ det_w, const float* __restrict__ det_b,
    const float* __restrict__ co_w1, const float* __restrict__ co_b1,
    const float* __restrict__ co_w2, const float* __restrict__ co_b2,
    const float* __restrict__ sz_w1, const float* __restrict__ sz_b1,
    const float* __restrict__ sz_w2, const float* __restrict__ sz_b2,
    const float* __restrict__ an_w1, const float* __restrict__ an_b1,
    const float* __restrict__ an_w2, const float* __restrict__ an_b2,
    const float* __restrict__ cls_w1, const float* __restrict__ cls_b1,
    const float* __restrict__ cls_w2, const float* __restrict__ cls_b2,
    const float* __restrict__ conf_w1, const float* __restrict__ conf_b1,
    const float* __restrict__ conf_w2, const float* __restrict__ conf_b2,
    float* __restrict__ out)
{
    __shared__ float local[128], feat[128], h[64];
    const int bk = blockIdx.x;
    const int b = bk / 100;
    const int t = threadIdx.x;
    const int idx = topi[bk];
    const float score = topv[bk];

    const int yy = idx / 160, xx = idx % 160;
    local[t] = features[((size_t)b * 128 + t) * (160 * 162) + (size_t)yy * 162 + (xx + 1)];
    __syncthreads();

    {
        float a = det_b[t];
        const float* wr = det_w + (size_t)t * 128;
#pragma unroll
        for (int i = 0; i < 128; ++i) a = fmaf(local[i], wr[i], a);
        feat[t] = fmaxf(a, 0.f);
    }
    __syncthreads();

    if (t < 32) {
        float a = co_b1[t];
        const float* wr = co_w1 + (size_t)t * 128;
#pragma unroll
        for (int i = 0; i < 128; ++i) a = fmaf(feat[i], wr[i], a);
        h[t] = fmaxf(a, 0.f);
    }
    __syncthreads();
    if (t < 2) {
        float a = co_b2[t];
        const float* wr = co_w2 + (size_t)t * 32;
#pragma unroll
        for (int j = 0; j < 32; ++j) a = fmaf(h[j], wr[j], a);
        const float off = tanhf(a);
        const float coord = (t == 0) ? (float)xx * (1.f / 160.f) : (float)yy * (1.f / 160.f);
        out[OFF_CENTERS + bk * 2 + t] = (coord + off * (1.f / 160.f)) * 640.f;
    }
    __syncthreads();

    if (t < 32) {
        float a = sz_b1[t];
        const float* wr = sz_w1 + (size_t)t * 128;
#pragma unroll
        for (int i = 0; i < 128; ++i) a = fmaf(feat[i], wr[i], a);
        h[t] = fmaxf(a, 0.f);
    }
    __syncthreads();
    if (t < 2) {
        float a = sz_b2[t];
        const float* wr = sz_w2 + (size_t)t * 32;
#pragma unroll
        for (int j = 0; j < 32; ++j) a = fmaf(h[j], wr[j], a);
        a = fminf(fmaxf(a, -5.f), 5.f);
        out[OFF_WH + bk * 2 + t] = expf(a) * 64.f;
    }
    __syncthreads();

    if (t < 16) {
        float a = an_b1[t];
        const float* wr = an_w1 + (size_t)t * 128;
#pragma unroll
        for (int i = 0; i < 128; ++i) a = fmaf(feat[i], wr[i], a);
        h[t] = fmaxf(a, 0.f);
    }
    __syncthreads();
    if (t == 0) {
        float a = an_b2[0];
#pragma unroll
        for (int j = 0; j < 16; ++j) a = fmaf(h[j], an_w2[j], a);
        out[OFF_ANG + bk] = atan2f(sinf(a), cosf(a));
    }
    __syncthreads();

    if (t < 64) {
        float a = cls_b1[t];
        const float* wr = cls_w1 + (size_t)t * 128;
#pragma unroll
        for (int i = 0; i < 128; ++i) a = fmaf(feat[i], wr[i], a);
        h[t] = fmaxf(a, 0.f);
    }
    __syncthreads();
    if (t < 15) {
        float a = cls_b2[t];
        const float* wr = cls_w2 + (size_t)t * 64;
#pragma unroll
        for (int j = 0; j < 64; ++j) a = fmaf(h[j], wr[j], a);
        out[OFF_CLS + bk * 15 + t] = a;
    }
    __syncthreads();

    if (t < 16) {
        float a = conf_b1[t];
        const float* wr = conf_w1 + (size_t)t * 129;
#pragma unroll
        for (int i = 0; i < 128; ++i) a = fmaf(feat[i], wr[i], a);
        a = fmaf(score, wr[128], a);
        h[t] = fmaxf(a, 0.f);
    }
    __syncthreads();
    if (t == 0) {
        float a = conf_b2[0];
#pragma unroll
        for (int j = 0; j < 16; ++j) a = fmaf(h[j], conf_w2[j], a);
        out[OFF_CONF + bk] = 1.f / (1.f + expf(-a));
    }
}

extern "C" void kernel_launch(void* const* d_in, const int* in_sizes, int n_in,
                              void* d_out, int out_size, void* d_ws, size_t ws_size,
                              hipStream_t stream)
{
    const float* images = (const float*)d_in[0];
    const float* enc_w1 = (const float*)d_in[1];
    const float* enc_b1 = (const float*)d_in[2];
    const float* bn1_g  = (const float*)d_in[3];
    const float* bn1_b  = (const float*)d_in[4];
    const float* enc_w2 = (const float*)d_in[5];
    const float* enc_b2 = (const float*)d_in[6];
    const float* bn2_g  = (const float*)d_in[7];
    const float* bn2_b  = (const float*)d_in[8];
    const float* enc_w3 = (const float*)d_in[9];
    const float* enc_b3 = (const float*)d_in[10];
    const float* bn3_g  = (const float*)d_in[11];
    const float* bn3_b  = (const float*)d_in[12];
    const float* dist_w1 = (const float*)d_in[13];
    const float* dist_b1 = (const float*)d_in[14];
    const float* dist_w2 = (const float*)d_in[15];
    const float* dist_b2 = (const float*)d_in[16];
    const float* feat_w = (const float*)d_in[17];
    const float* feat_b = (const float*)d_in[18];
    const float* bnf_g  = (const float*)d_in[19];
    const float* bnf_b  = (const float*)d_in[20];
    const float* temperature = (const float*)d_in[21];
    const float* score_w1 = (const float*)d_in[22];
    const float* score_b1 = (const float*)d_in[23];
    const float* score_w2 = (const float*)d_in[24];
    const float* score_b2 = (const float*)d_in[25];
    const float* det_w = (const float*)d_in[26];
    const float* det_b = (const float*)d_in[27];
    const float* co_w1 = (const float*)d_in[28];
    const float* co_b1 = (const float*)d_in[29];
    const float* co_w2 = (const float*)d_in[30];
    const float* co_b2 = (const float*)d_in[31];
    const float* sz_w1 = (const float*)d_in[32];
    const float* sz_b1 = (const float*)d_in[33];
    const float* sz_w2 = (const float*)d_in[34];
    const float* sz_b2 = (const float*)d_in[35];
    const float* an_w1 = (const float*)d_in[36];
    const float* an_b1 = (const float*)d_in[37];
    const float* an_w2 = (const float*)d_in[38];
    const float* an_b2 = (const float*)d_in[39];
    const float* cls_w1 = (const float*)d_in[40];
    const float* cls_b1 = (const float*)d_in[41];
    const float* cls_w2 = (const float*)d_in[42];
    const float* cls_b2 = (const float*)d_in[43];
    const float* conf_w1 = (const float*)d_in[44];
    const float* conf_b1 = (const float*)d_in[45];
    const float* conf_w2 = (const float*)d_in[46];
    const float* conf_b2 = (const float*)d_in[47];

    float* out = (float*)d_out;

    // ---- workspace layout: ~254.8 MiB (< 256 MiB)
    float* Wk = (float*)d_ws;
    size_t off = 0;
    auto alloc = [&](size_t n) { float* p = Wk + off; off += n; return p; };
    float* wt1 = alloc(27 * 32);    float* b1 = alloc(32);
    float* wt2 = alloc(288 * 64);   float* b2 = alloc(64);
    float* wt3 = alloc(576 * 128);  float* b3 = alloc(128);
    float* wtf = alloc(1152 * 128); float* bf = alloc(128);
    float* wtd = alloc(1152 * 64);
    float* wts = alloc(1161 * 64);
    float* zrow = alloc(32);                         // 16B-aligned zero row (NL<=9)
    // slotA: P1 conv1-out (8,32,320,322)=26,378,240 -> then PF feat-out (8,128,160,162)=26,542,080
    float* slotA = alloc(26542080);
    // slotB: P2 conv2-out (8,64,160,162)=13,271,040 -> then DH/SH (8,64,160,160)=13,107,200 + fisher_pad tail
    float* slotB = alloc(13314560);
    // slotC: P3 conv3-out (8,128,160,162) -> later scores+topi at base (after P3 dead)
    float* slotC = alloc(26542080);
    float* fisher_pad = slotB + 13107200;            // (8,160,162)=207,360
    float* scores = slotC;                           // 204,800
    int*   topi   = (int*)(slotC + 204800);          // 800

    auto g256 = [](int n) { return dim3((n + 255) / 256); };

    // --- fused weight/bias prep (1 launch) + fused pad zeroing (1 launch)
    prep_all_k<<<g256(388864), 256, 0, stream>>>(
        enc_w1, bn1_g, enc_w2, bn2_g, enc_w3, bn3_g, feat_w, bnf_g,
        dist_w1, score_w1,
        enc_b1, bn1_b, enc_b2, bn2_b, enc_b3, bn3_b, feat_b, bnf_b,
        wt1, wt2, wt3, wtf, wtd, wts, b1, b2, b3, bf);
    zero_pads_k<<<g256(655392), 256, 0, stream>>>(zrow, slotA, slotB, slotC);

    // --- encoder
    conv3x3_k<3, 32, 32, 2, 320, 320, ACT_GELU, true>
        <<<dim3(20, 20, 8), 256, 0, stream>>>(images, wt1, b1, slotA);
    conv4_k<32, 64, 2, 322, 320, ACT_GELU, false, true>
        <<<dim3(5, 5, 8 * 4), 256, 0, stream>>>(slotA, nullptr, wt2, b2, zrow, slotB);
    // slotA now free -> becomes PF; zero its pad cols (must be AFTER conv2 reads P1)
    zero_cols_k<<<g256(1024 * 160 * 2), 256, 0, stream>>>(slotA, 8 * 128, 162, 160);
    conv4_k<64, 128, 1, 162, 160, ACT_GELU, false, true>
        <<<dim3(5, 5, 8 * 8), 256, 0, stream>>>(slotB, nullptr, wt3, b3, zrow, slotC);

    // --- dist branch -> fisher map (unpadded straight to d_out + x-padded copy)
    conv4_k<128, 64, 1, 162, 160, ACT_RELU, false, false>
        <<<dim3(5, 5, 8 * 4), 256, 0, stream>>>(slotC, nullptr, wtd, dist_b1, zrow, slotB);
    zero_fill_k<<<g256(207360), 256, 0, stream>>>(fisher_pad, 207360);
    dist2_fisher_k<<<800, 256, 0, stream>>>(slotB, dist_w2, dist_b2, temperature,
                                            out + OFF_FISH, fisher_pad);

    // --- features (x-padded into slotA)
    conv4_k<128, 128, 1, 162, 160, ACT_GELU, false, true>
        <<<dim3(5, 5, 8 * 8), 256, 0, stream>>>(slotC, nullptr, wtf, bf, zrow, slotA);

    // --- score branch (features + fisher extra channel)
    conv4_k<128, 64, 1, 162, 160, ACT_RELU, true, false>
        <<<dim3(5, 5, 8 * 4), 256, 0, stream>>>(slotA, fisher_pad, wts, score_b1, zrow, slotB);
    score2_k<<<800, 256, 0, stream>>>(slotB, score_w2, score_b2, scores);

    // --- top-100 per batch (radix select)
    topk_radix_k<<<8, 256, 0, stream>>>(scores, out + OFF_TOPS, topi);

    // --- proposal heads (x-padded feature gather)
    heads_k<<<800, 128, 0, stream>>>(slotA, out + OFF_TOPS, topi,
                                     det_w, det_b, co_w1, co_b1, co_w2, co_b2,
                                     sz_w1, sz_b1, sz_w2, sz_b2,
                                     an_w1, an_b1, an_w2, an_b2,
                                     cls_w1, cls_b1, cls_w2, cls_b2,
                                     conf_w1, conf_b1, conf_w2, conf_b2, out);
    (void)in_sizes; (void)n_in; (void)out_size; (void)ws_size;
}

// Round 9
// 2246.209 us; speedup vs baseline: 1.1851x; 1.1851x over previous
//
#include <hip/hip_runtime.h>
#include <cmath>

#define ACT_NONE 0
#define ACT_GELU 1
#define ACT_RELU 2

// d_out layout (floats):
//  centers[0,1600) wh[1600,3200) angles[3200,4000) cls[4000,16000)
//  conf[16000,16800) tops[16800,17600) fisher[17600,222400)
#define OFF_CENTERS 0
#define OFF_WH      1600
#define OFF_ANG     3200
#define OFF_CLS     4000
#define OFF_CONF    16000
#define OFF_TOPS    16800
#define OFF_FISH    17600

__device__ __forceinline__ float gelu_f(float v) {
    return 0.5f * v * (1.f + erff(v * 0.70710678118654752f));
}

// ---------------- fused prep: all weight transposes (BN-folded) + biases in ONE launch
__device__ __forceinline__ void wtr_seg(const float* __restrict__ w, const float* __restrict__ g,
                                        float* __restrict__ dst, int O, int I9, int j) {
    const int o = j / I9, r = j % I9;
    float s = 1.f;
    if (g) {
        double sq = sqrt(1.0 + 1e-5);
        s = g[o] / (float)sq;
    }
    dst[(size_t)r * O + o] = w[(size_t)o * I9 + r] * s;
}
__device__ __forceinline__ void btr_seg(const float* __restrict__ b, const float* __restrict__ g,
                                        const float* __restrict__ bb, float* __restrict__ dst, int o) {
    double sq = sqrt(1.0 + 1e-5);
    const float s = g[o] / (float)sq;
    dst[o] = b[o] * s + bb[o];
}

__global__ __launch_bounds__(256) void prep_all_k(
    const float* ew1, const float* g1, const float* ew2, const float* g2,
    const float* ew3, const float* g3, const float* fw,  const float* gf,
    const float* dw,  const float* sw,
    const float* eb1, const float* bb1, const float* eb2, const float* bb2,
    const float* eb3, const float* bb3, const float* fb,  const float* bbf,
    float* wt1, float* wt2, float* wt3, float* wtf, float* wtd, float* wts,
    float* ob1, float* ob2, float* ob3, float* obf)
{
    int i = blockIdx.x * 256 + threadIdx.x;
    if (i < 864)    { wtr_seg(ew1, g1, wt1, 32, 27, i);    return; }  i -= 864;
    if (i < 18432)  { wtr_seg(ew2, g2, wt2, 64, 288, i);   return; }  i -= 18432;
    if (i < 73728)  { wtr_seg(ew3, g3, wt3, 128, 576, i);  return; }  i -= 73728;
    if (i < 147456) { wtr_seg(fw,  gf, wtf, 128, 1152, i); return; }  i -= 147456;
    if (i < 73728)  { wtr_seg(dw, nullptr, wtd, 64, 1152, i); return; } i -= 73728;
    if (i < 74304)  { wtr_seg(sw, nullptr, wts, 64, 1161, i); return; } i -= 74304;
    if (i < 32)     { btr_seg(eb1, g1, bb1, ob1, i); return; }  i -= 32;
    if (i < 64)     { btr_seg(eb2, g2, bb2, ob2, i); return; }  i -= 64;
    if (i < 128)    { btr_seg(eb3, g3, bb3, ob3, i); return; }  i -= 128;
    if (i < 128)    { btr_seg(fb,  gf, bbf, obf, i); return; }
}

// ---------------- zero helpers
__device__ __forceinline__ void zcol(float* __restrict__ buf, int W, int H, int j) {
    const int p = j / (H * 2), r = j % (H * 2);
    const int y = r >> 1, side = r & 1;
    buf[(size_t)p * W * H + (size_t)y * W + (side ? W - 1 : 0)] = 0.f;
}

// upfront: zrow + P1/P2/P3 pad columns in ONE launch
__global__ __launch_bounds__(256) void zero_pads_k(
    float* zrow, float* p1, float* p2, float* p3)
{
    int i = blockIdx.x * 256 + threadIdx.x;
    if (i < 32) { zrow[i] = 0.f; return; }          i -= 32;
    if (i < 256 * 320 * 2)  { zcol(p1, 322, 320, i); return; }  i -= 256 * 320 * 2;
    if (i < 512 * 160 * 2)  { zcol(p2, 162, 160, i); return; }  i -= 512 * 160 * 2;
    if (i < 1024 * 160 * 2) { zcol(p3, 162, 160, i); return; }
}

__global__ void zero_cols_k(float* __restrict__ buf, int nplanes, int W, int H) {
    int i = blockIdx.x * 256 + threadIdx.x;
    if (i >= nplanes * H * 2) return;
    zcol(buf, W, H, i);
}

__global__ void zero_fill_k(float* __restrict__ buf, int n) {
    int i = blockIdx.x * 256 + threadIdx.x;
    if (i < n) buf[i] = 0.f;
}

// ---------------- checked direct conv (conv1 only: 3->32, stride2, raw images)
template<int CIN, int COUT, int CHUNK, int STRIDE, int HOUT, int WOUT, int ACT, bool OPADX>
__global__ __launch_bounds__(256) void conv3x3_k(
    const float* __restrict__ in, const float* __restrict__ wt,
    const float* __restrict__ bias, float* __restrict__ out)
{
    constexpr int HIN = HOUT * STRIDE, WIN = WOUT * STRIDE;
    constexpr int NCH = COUT / CHUNK;
    const int tx = threadIdx.x & 15, ty = threadIdx.x >> 4;
    const int x = blockIdx.x * 16 + tx;
    const int y = blockIdx.y * 16 + ty;
    const int b = blockIdx.z / NCH;
    const int co0 = (blockIdx.z % NCH) * CHUNK;

    float acc[CHUNK];
#pragma unroll
    for (int c = 0; c < CHUNK; ++c) acc[c] = bias[co0 + c];

    const float* inb = in + (size_t)b * CIN * HIN * WIN;
#pragma unroll 1
    for (int ci = 0; ci < CIN; ++ci) {
        const float* ip = inb + (size_t)ci * HIN * WIN;
#pragma unroll
        for (int ky = 0; ky < 3; ++ky) {
            const int iy = y * STRIDE + ky - 1;
            const bool yok = (unsigned)iy < (unsigned)HIN;
#pragma unroll
            for (int kx = 0; kx < 3; ++kx) {
                const int ix = x * STRIDE + kx - 1;
                const bool ok = yok && ((unsigned)ix < (unsigned)WIN);
                const float v = ok ? ip[(size_t)iy * WIN + ix] : 0.f;
                const float* wp = wt + ((size_t)(ci * 9 + ky * 3 + kx)) * COUT + co0;
#pragma unroll
                for (int c = 0; c < CHUNK; ++c) acc[c] = fmaf(v, wp[c], acc[c]);
            }
        }
    }
#pragma unroll
    for (int c = 0; c < CHUNK; ++c) {
        float v = acc[c];
        if (ACT == ACT_GELU) v = gelu_f(v);
        if (ACT == ACT_RELU) v = fmaxf(v, 0.f);
        if (OPADX) {
            out[((size_t)b * COUT + co0 + c) * (size_t)(HOUT * (WOUT + 2))
                + (size_t)y * (WOUT + 2) + (x + 1)] = v;
        } else {
            out[((size_t)b * COUT + co0 + c) * (size_t)(HOUT * WOUT)
                + (size_t)y * WOUT + x] = v;
        }
    }
}

// ---------------- x-padded conv v5: scalar (SGPR) weights, P=2 px strips,
// 16-cout chunk, 32 accumulators -> small unified-register footprint -> high TLP.
// (R8 lesson: manual ILP prefetch costs waves; TLP does the hiding here.)
#define FMA16(A, V, W0, W1, W2, W3) do { \
  A[0]=fmaf((V),(W0).x,A[0]); A[1]=fmaf((V),(W0).y,A[1]); A[2]=fmaf((V),(W0).z,A[2]); A[3]=fmaf((V),(W0).w,A[3]); \
  A[4]=fmaf((V),(W1).x,A[4]); A[5]=fmaf((V),(W1).y,A[5]); A[6]=fmaf((V),(W1).z,A[6]); A[7]=fmaf((V),(W1).w,A[7]); \
  A[8]=fmaf((V),(W2).x,A[8]); A[9]=fmaf((V),(W2).y,A[9]); A[10]=fmaf((V),(W2).z,A[10]); A[11]=fmaf((V),(W2).w,A[11]); \
  A[12]=fmaf((V),(W3).x,A[12]); A[13]=fmaf((V),(W3).y,A[13]); A[14]=fmaf((V),(W3).z,A[14]); A[15]=fmaf((V),(W3).w,A[15]); \
} while (0)

// in: x-padded (B,CIN,HIN,PW), zero cols 0 & PW-1; rows via zero-row pointer select.
// out 160x160: OPAD -> x-padded (160x162), else unpadded (160x160).
template<int CIN, int COUT, int S, int PW, int HIN, int ACT, bool EXTRA, bool OPAD>
__global__ __launch_bounds__(256) void conv2p_k(
    const float* __restrict__ in, const float* __restrict__ extra,
    const float* __restrict__ wt, const float* __restrict__ bias,
    const float* __restrict__ zrow, float* __restrict__ out)
{
    constexpr int PPIN = HIN * PW;
    constexpr int CHUNK = 16, NCH = COUT / CHUNK;
    constexpr int CTOT = CIN + (EXTRA ? 1 : 0);
    constexpr int NL = S + 3;   // 4 (S=1) or 5 (S=2)
    const int tx = threadIdx.x & 7, ty = threadIdx.x >> 3;
    const int ox0 = blockIdx.x * 16 + tx * 2;          // 2 output px per thread
    const int oy  = blockIdx.y * 32 + ty;
    const int b   = blockIdx.z / NCH;
    const int co0 = (blockIdx.z % NCH) * CHUNK;

    float acc[2][16];
#pragma unroll
    for (int c = 0; c < 16; ++c) {
        const float bv = bias[co0 + c];
        acc[0][c] = bv; acc[1][c] = bv;
    }

    int rowoff[3], rok[3];
#pragma unroll
    for (int r = 0; r < 3; ++r) {
        const int riy = oy * S + r - 1;
        rok[r] = (riy >= 0 && riy < HIN) ? 1 : 0;
        const int rr = riy < 0 ? 0 : (riy >= HIN ? HIN - 1 : riy);
        rowoff[r] = rr * PW + ox0 * S;      // even -> float2-aligned
    }

    const float* inb = in + (size_t)b * CIN * PPIN;
    const float* wb  = wt + co0;

#pragma unroll 1
    for (int ci = 0; ci < CTOT; ++ci) {
        const float* chp = (EXTRA && ci == CIN) ? (extra + (size_t)b * PPIN)
                                                : (inb + (size_t)ci * PPIN);
        float v[3][NL];
#pragma unroll
        for (int r = 0; r < 3; ++r) {
            const float* pr = rok[r] ? (chp + rowoff[r]) : zrow;
#pragma unroll
            for (int j = 0; j < NL / 2; ++j) {
                const float2 t = *(const float2*)(pr + 2 * j);
                v[r][2 * j] = t.x; v[r][2 * j + 1] = t.y;
            }
            if (NL & 1) v[r][NL - 1] = pr[NL - 1];
        }
        const float* wr = wb + (size_t)(ci * 9) * COUT;
#pragma unroll
        for (int ky = 0; ky < 3; ++ky) {
#pragma unroll
            for (int kx = 0; kx < 3; ++kx) {
                const float* wp = wr + (size_t)(ky * 3 + kx) * COUT;  // uniform -> SGPR
                const float4 w0 = *(const float4*)(wp);
                const float4 w1 = *(const float4*)(wp + 4);
                const float4 w2 = *(const float4*)(wp + 8);
                const float4 w3 = *(const float4*)(wp + 12);
                const float a0 = v[ky][kx];
                const float a1 = v[ky][kx + S];
                FMA16(acc[0], a0, w0, w1, w2, w3);
                FMA16(acc[1], a1, w0, w1, w2, w3);
            }
        }
    }

#pragma unroll
    for (int c = 0; c < 16; ++c) {
#pragma unroll
        for (int p = 0; p < 2; ++p) {
            float u = acc[p][c];
            if (ACT == ACT_GELU) u = gelu_f(u);
            if (ACT == ACT_RELU) u = fmaxf(u, 0.f);
            if (OPAD) {
                out[((size_t)b * COUT + co0 + c) * (160 * 162)
                    + (size_t)oy * 162 + (ox0 + p + 1)] = u;
            } else {
                out[((size_t)b * COUT + co0 + c) * (160 * 160)
                    + (size_t)oy * 160 + (ox0 + p)] = u;
            }
        }
    }
}

// ---------------- dist 1x1 conv (64->15) + analytic Fisher map, fused
__global__ __launch_bounds__(256) void dist2_fisher_k(
    const float* __restrict__ hid, const float* __restrict__ w /*15x64*/,
    const float* __restrict__ b2 /*15*/, const float* __restrict__ temp,
    float* __restrict__ fisher_out, float* __restrict__ fisher_pad)
{
    const int p = blockIdx.x * 256 + threadIdx.x;
    if (p >= 8 * 25600) return;
    const int bi = p / 25600, pix = p % 25600;
    const float* h = hid + (size_t)bi * 64 * 25600 + pix;
    float hv[64];
#pragma unroll
    for (int i = 0; i < 64; ++i) hv[i] = h[(size_t)i * 25600];
    const float t = fminf(fmaxf(temp[0], 0.1f), 10.f);
    const float inv_t = 1.f / t;
    float fsum = 0.f;
#pragma unroll 1
    for (int c = 0; c < 15; ++c) {
        float l = b2[c];
        const float* wr = w + c * 64;
#pragma unroll
        for (int i = 0; i < 64; ++i) l = fmaf(hv[i], wr[i], l);
        const float pr = 1.f / (1.f + expf(-l * inv_t));
        fsum += fmaxf(pr * (1.f - pr), 1e-6f);
    }
    fisher_out[p] = fsum;
    const int yy = pix / 160, xx = pix % 160;
    fisher_pad[(size_t)bi * (160 * 162) + (size_t)yy * 162 + (xx + 1)] = fsum;
}

// ---------------- score 1x1 conv (64->1) + sigmoid
__global__ __launch_bounds__(256) void score2_k(
    const float* __restrict__ hid, const float* __restrict__ w /*64*/,
    const float* __restrict__ b, float* __restrict__ sc)
{
    const int p = blockIdx.x * 256 + threadIdx.x;
    if (p >= 8 * 25600) return;
    const int bi = p / 25600, pix = p % 25600;
    const float* h = hid + (size_t)bi * 64 * 25600 + pix;
    float a = b[0];
#pragma unroll
    for (int i = 0; i < 64; ++i) a = fmaf(h[(size_t)i * 25600], w[i], a);
    sc[p] = 1.f / (1.f + expf(-a));
}

// ---------------- per-batch top-100 via 4-pass MSB radix select
#define TK_CAP 512
__global__ __launch_bounds__(256) void topk_radix_k(
    const float* __restrict__ scores, float* __restrict__ topv, int* __restrict__ topi)
{
    __shared__ unsigned hist[256];
    __shared__ unsigned gv[128]; __shared__ int gi[128];
    __shared__ unsigned ecnt[2];
    __shared__ int ei_[TK_CAP];
    __shared__ unsigned fv[100]; __shared__ int fi[100];
    __shared__ unsigned sel_prefix; __shared__ int sel_remaining;
    const int b = blockIdx.x, t = threadIdx.x;
    const float* s = scores + (size_t)b * 25600;

    unsigned prefix = 0; int remaining = 100;
    for (int pass = 0; pass < 4; ++pass) {
        const int shift = 24 - 8 * pass;
        hist[t] = 0;
        __syncthreads();
        const unsigned pmask = (pass == 0) ? 0u : (0xFFFFFFFFu << (shift + 8));
        for (int i = t; i < 25600; i += 256) {
            const unsigned k = __float_as_uint(s[i]);
            if ((k & pmask) == prefix)
                atomicAdd(&hist[(k >> shift) & 255], 1u);
        }
        __syncthreads();
        if (t == 0) {
            unsigned cum = 0; int bkt = 0;
            for (int d = 255; d >= 0; --d) {
                const unsigned c = hist[d];
                if (cum + c >= (unsigned)remaining) { bkt = d; break; }
                cum += c;
            }
            sel_prefix = prefix | ((unsigned)bkt << shift);
            sel_remaining = remaining - (int)cum;
        }
        __syncthreads();
        prefix = sel_prefix; remaining = sel_remaining;
        __syncthreads();
    }
    if (t == 0) { ecnt[0] = 0; ecnt[1] = 0; }
    __syncthreads();
    for (int i = t; i < 25600; i += 256) {
        const unsigned k = __float_as_uint(s[i]);
        if (k > prefix) {
            const unsigned p = atomicAdd(&ecnt[0], 1u);
            gv[p] = k; gi[p] = i;
        } else if (k == prefix) {
            const unsigned p = atomicAdd(&ecnt[1], 1u);
            if (p < TK_CAP) ei_[p] = i;
        }
    }
    __syncthreads();
    const int cG = (int)ecnt[0];
    const int cE = (int)ecnt[1] < TK_CAP ? (int)ecnt[1] : TK_CAP;
    if (t < cG) { fv[t] = gv[t]; fi[t] = gi[t]; }
    if (t < cE) {
        const int idx = ei_[t]; int r = 0;
        for (int l = 0; l < cE; ++l) r += (ei_[l] < idx) ? 1 : 0;
        if (r < remaining) { fv[cG + r] = prefix; fi[cG + r] = idx; }
    }
    __syncthreads();
    if (t < 100) {
        const unsigned myv = fv[t]; const int myi = fi[t]; int r = 0;
        for (int l = 0; l < 100; ++l) {
            const unsigned v = fv[l]; const int li = fi[l];
            r += (v > myv || (v == myv && li < myi)) ? 1 : 0;
        }
        topv[b * 100 + r] = __uint_as_float(myv);
        topi[b * 100 + r] = myi;
    }
}

// ---------------- per-proposal heads: one block per (b,k), 128 threads
// features is x-padded (B,128,160,162)
__global__ __launch_bounds__(128) void heads_k(
    const float* __restrict__ features, const float* __restrict__ topv,
    const int* __restrict__ topi,
    const float* __restrict__ det_w, const float* __restrict__ det_b,
    const float* __restrict__ co_w1, const float* __restrict__ co_b1,
    const float* __restrict__ co_w2, const float* __restrict__ co_b2,
    const float* __restrict__ sz_w1, const float* __restrict__ sz_b1,
    const float* __restrict__ sz_w2, const float* __restrict__ sz_b2,
    const float* __restrict__ an_w1, const float* __restrict__ an_b1,
    const float* __restrict__ an_w2, const float* __restrict__ an_b2,
    const float* __restrict__ cls_w1, const float* __restrict__ cls_b1,
    const float* __restrict__ cls_w2, const float* __restrict__ cls_b2,
    const float* __restrict__ conf_w1, const float* __restrict__ conf_b1,
    const float* __restrict__ conf_w2, const float* __restrict__ conf_b2,
    float* __restrict__ out)
{
    __shared__ float local[128], feat[128], h[64];
    const int bk = blockIdx.x;
    const int b = bk / 100;
    const int t = threadIdx.x;
    const int idx = topi[bk];
    const float score = topv[bk];

    const int yy = idx / 160, xx = idx % 160;
    local[t] = features[((size_t)b * 128 + t) * (160 * 162) + (size_t)yy * 162 + (xx + 1)];
    __syncthreads();

    {
        float a = det_b[t];
        const float* wr = det_w + (size_t)t * 128;
#pragma unroll
        for (int i = 0; i < 128; ++i) a = fmaf(local[i], wr[i], a);
        feat[t] = fmaxf(a, 0.f);
    }
    __syncthreads();

    if (t < 32) {
        float a = co_b1[t];
        const float* wr = co_w1 + (size_t)t * 128;
#pragma unroll
        for (int i = 0; i < 128; ++i) a = fmaf(feat[i], wr[i], a);
        h[t] = fmaxf(a, 0.f);
    }
    __syncthreads();
    if (t < 2) {
        float a = co_b2[t];
        const float* wr = co_w2 + (size_t)t * 32;
#pragma unroll
        for (int j = 0; j < 32; ++j) a = fmaf(h[j], wr[j], a);
        const float off = tanhf(a);
        const float coord = (t == 0) ? (float)xx * (1.f / 160.f) : (float)yy * (1.f / 160.f);
        out[OFF_CENTERS + bk * 2 + t] = (coord + off * (1.f / 160.f)) * 640.f;
    }
    __syncthreads();

    if (t < 32) {
        float a = sz_b1[t];
        const float* wr = sz_w1 + (size_t)t * 128;
#pragma unroll
        for (int i = 0; i < 128; ++i) a = fmaf(feat[i], wr[i], a);
        h[t] = fmaxf(a, 0.f);
    }
    __syncthreads();
    if (t < 2) {
        float a = sz_b2[t];
        const float* wr = sz_w2 + (size_t)t * 32;
#pragma unroll
        for (int j = 0; j < 32; ++j) a = fmaf(h[j], wr[j], a);
        a = fminf(fmaxf(a, -5.f), 5.f);
        out[OFF_WH + bk * 2 + t] = expf(a) * 64.f;
    }
    __syncthreads();

    if (t < 16) {
        float a = an_b1[t];
        const float* wr = an_w1 + (size_t)t * 128;
#pragma unroll
        for (int i = 0; i < 128; ++i) a = fmaf(feat[i], wr[i], a);
        h[t] = fmaxf(a, 0.f);
    }
    __syncthreads();
    if (t == 0) {
        float a = an_b2[0];
#pragma unroll
        for (int j = 0; j < 16; ++j) a = fmaf(h[j], an_w2[j], a);
        out[OFF_ANG + bk] = atan2f(sinf(a), cosf(a));
    }
    __syncthreads();

    if (t < 64) {
        float a = cls_b1[t];
        const float* wr = cls_w1 + (size_t)t * 128;
#pragma unroll
        for (int i = 0; i < 128; ++i) a = fmaf(feat[i], wr[i], a);
        h[t] = fmaxf(a, 0.f);
    }
    __syncthreads();
    if (t < 15) {
        float a = cls_b2[t];
        const float* wr = cls_w2 + (size_t)t * 64;
#pragma unroll
        for (int j = 0; j < 64; ++j) a = fmaf(h[j], wr[j], a);
        out[OFF_CLS + bk * 15 + t] = a;
    }
    __syncthreads();

    if (t < 16) {
        float a = conf_b1[t];
        const float* wr = conf_w1 + (size_t)t * 129;
#pragma unroll
        for (int i = 0; i < 128; ++i) a = fmaf(feat[i], wr[i], a);
        a = fmaf(score, wr[128], a);
        h[t] = fmaxf(a, 0.f);
    }
    __syncthreads();
    if (t == 0) {
        float a = conf_b2[0];
#pragma unroll
        for (int j = 0; j < 16; ++j) a = fmaf(h[j], conf_w2[j], a);
        out[OFF_CONF + bk] = 1.f / (1.f + expf(-a));
    }
}

extern "C" void kernel_launch(void* const* d_in, const int* in_sizes, int n_in,
                              void* d_out, int out_size, void* d_ws, size_t ws_size,
                              hipStream_t stream)
{
    const float* images = (const float*)d_in[0];
    const float* enc_w1 = (const float*)d_in[1];
    const float* enc_b1 = (const float*)d_in[2];
    const float* bn1_g  = (const float*)d_in[3];
    const float* bn1_b  = (const float*)d_in[4];
    const float* enc_w2 = (const float*)d_in[5];
    const float* enc_b2 = (const float*)d_in[6];
    const float* bn2_g  = (const float*)d_in[7];
    const float* bn2_b  = (const float*)d_in[8];
    const float* enc_w3 = (const float*)d_in[9];
    const float* enc_b3 = (const float*)d_in[10];
    const float* bn3_g  = (const float*)d_in[11];
    const float* bn3_b  = (const float*)d_in[12];
    const float* dist_w1 = (const float*)d_in[13];
    const float* dist_b1 = (const float*)d_in[14];
    const float* dist_w2 = (const float*)d_in[15];
    const float* dist_b2 = (const float*)d_in[16];
    const float* feat_w = (const float*)d_in[17];
    const float* feat_b = (const float*)d_in[18];
    const float* bnf_g  = (const float*)d_in[19];
    const float* bnf_b  = (const float*)d_in[20];
    const float* temperature = (const float*)d_in[21];
    const float* score_w1 = (const float*)d_in[22];
    const float* score_b1 = (const float*)d_in[23];
    const float* score_w2 = (const float*)d_in[24];
    const float* score_b2 = (const float*)d_in[25];
    const float* det_w = (const float*)d_in[26];
    const float* det_b = (const float*)d_in[27];
    const float* co_w1 = (const float*)d_in[28];
    const float* co_b1 = (const float*)d_in[29];
    const float* co_w2 = (const float*)d_in[30];
    const float* co_b2 = (const float*)d_in[31];
    const float* sz_w1 = (const float*)d_in[32];
    const float* sz_b1 = (const float*)d_in[33];
    const float* sz_w2 = (const float*)d_in[34];
    const float* sz_b2 = (const float*)d_in[35];
    const float* an_w1 = (const float*)d_in[36];
    const float* an_b1 = (const float*)d_in[37];
    const float* an_w2 = (const float*)d_in[38];
    const float* an_b2 = (const float*)d_in[39];
    const float* cls_w1 = (const float*)d_in[40];
    const float* cls_b1 = (const float*)d_in[41];
    const float* cls_w2 = (const float*)d_in[42];
    const float* cls_b2 = (const float*)d_in[43];
    const float* conf_w1 = (const float*)d_in[44];
    const float* conf_b1 = (const float*)d_in[45];
    const float* conf_w2 = (const float*)d_in[46];
    const float* conf_b2 = (const float*)d_in[47];

    float* out = (float*)d_out;

    // ---- workspace layout: ~254.8 MiB (< 256 MiB)
    float* Wk = (float*)d_ws;
    size_t off = 0;
    auto alloc = [&](size_t n) { float* p = Wk + off; off += n; return p; };
    float* wt1 = alloc(27 * 32);    float* b1 = alloc(32);
    float* wt2 = alloc(288 * 64);   float* b2 = alloc(64);
    float* wt3 = alloc(576 * 128);  float* b3 = alloc(128);
    float* wtf = alloc(1152 * 128); float* bf = alloc(128);
    float* wtd = alloc(1152 * 64);
    float* wts = alloc(1161 * 64);
    float* zrow = alloc(32);                         // 16B-aligned zero row (NL<=9)
    // slotA: P1 conv1-out (8,32,320,322)=26,378,240 -> then PF feat-out (8,128,160,162)=26,542,080
    float* slotA = alloc(26542080);
    // slotB: P2 conv2-out (8,64,160,162)=13,271,040 -> then DH/SH (8,64,160,160)=13,107,200 + fisher_pad tail
    float* slotB = alloc(13314560);
    // slotC: P3 conv3-out (8,128,160,162) -> later scores+topi at base (after P3 dead)
    float* slotC = alloc(26542080);
    float* fisher_pad = slotB + 13107200;            // (8,160,162)=207,360
    float* scores = slotC;                           // 204,800
    int*   topi   = (int*)(slotC + 204800);          // 800

    auto g256 = [](int n) { return dim3((n + 255) / 256); };

    // --- fused weight/bias prep (1 launch) + fused pad zeroing (1 launch)
    prep_all_k<<<g256(388864), 256, 0, stream>>>(
        enc_w1, bn1_g, enc_w2, bn2_g, enc_w3, bn3_g, feat_w, bnf_g,
        dist_w1, score_w1,
        enc_b1, bn1_b, enc_b2, bn2_b, enc_b3, bn3_b, feat_b, bnf_b,
        wt1, wt2, wt3, wtf, wtd, wts, b1, b2, b3, bf);
    zero_pads_k<<<g256(655392), 256, 0, stream>>>(zrow, slotA, slotB, slotC);

    // --- encoder
    conv3x3_k<3, 32, 32, 2, 320, 320, ACT_GELU, true>
        <<<dim3(20, 20, 8), 256, 0, stream>>>(images, wt1, b1, slotA);
    conv2p_k<32, 64, 2, 322, 320, ACT_GELU, false, true>
        <<<dim3(10, 5, 8 * 4), 256, 0, stream>>>(slotA, nullptr, wt2, b2, zrow, slotB);
    // slotA now free -> becomes PF; zero its pad cols (must be AFTER conv2 reads P1)
    zero_cols_k<<<g256(1024 * 160 * 2), 256, 0, stream>>>(slotA, 8 * 128, 162, 160);
    conv2p_k<64, 128, 1, 162, 160, ACT_GELU, false, true>
        <<<dim3(10, 5, 8 * 8), 256, 0, stream>>>(slotB, nullptr, wt3, b3, zrow, slotC);

    // --- dist branch -> fisher map (unpadded straight to d_out + x-padded copy)
    conv2p_k<128, 64, 1, 162, 160, ACT_RELU, false, false>
        <<<dim3(10, 5, 8 * 4), 256, 0, stream>>>(slotC, nullptr, wtd, dist_b1, zrow, slotB);
    zero_fill_k<<<g256(207360), 256, 0, stream>>>(fisher_pad, 207360);
    dist2_fisher_k<<<800, 256, 0, stream>>>(slotB, dist_w2, dist_b2, temperature,
                                            out + OFF_FISH, fisher_pad);

    // --- features (x-padded into slotA)
    conv2p_k<128, 128, 1, 162, 160, ACT_GELU, false, true>
        <<<dim3(10, 5, 8 * 8), 256, 0, stream>>>(slotC, nullptr, wtf, bf, zrow, slotA);

    // --- score branch (features + fisher extra channel)
    conv2p_k<128, 64, 1, 162, 160, ACT_RELU, true, false>
        <<<dim3(10, 5, 8 * 4), 256, 0, stream>>>(slotA, fisher_pad, wts, score_b1, zrow, slotB);
    score2_k<<<800, 256, 0, stream>>>(slotB, score_w2, score_b2, scores);

    // --- top-100 per batch (radix select)
    topk_radix_k<<<8, 256, 0, stream>>>(scores, out + OFF_TOPS, topi);

    // --- proposal heads (x-padded feature gather)
    heads_k<<<800, 128, 0, stream>>>(slotA, out + OFF_TOPS, topi,
                                     det_w, det_b, co_w1, co_b1, co_w2, co_b2,
                                     sz_w1, sz_b1, sz_w2, sz_b2,
                                     an_w1, an_b1, an_w2, an_b2,
                                     cls_w1, cls_b1, cls_w2, cls_b2,
                                     conf_w1, conf_b1, conf_w2, conf_b2, out);
    (void)in_sizes; (void)n_in; (void)out_size; (void)ws_size;
}